// Round 1
// baseline (3180.557 us; speedup 1.0000x reference)
//
#include <hip/hip_runtime.h>
#include <hip/hip_bf16.h>

// ---------------- problem constants ----------------
#define EMBN   512
#define HIDN   1024
#define OUTN   512
#define BBN    64
#define SSN    256
#define NBLK   256          // persistent blocks; block j owns 4 h-dims x 4 gates = 16 preact cols
#define PSTR   20           // preact LDS row stride (floats)

typedef __attribute__((ext_vector_type(8))) short bf16x8;
typedef __attribute__((ext_vector_type(4))) float f32x4;
typedef unsigned short us;
typedef unsigned long long ull;

static __device__ __forceinline__ us f2bf(float x) {
  unsigned int u = __float_as_uint(x);
  unsigned int r = (u + 0x7fffu + ((u >> 16) & 1u)) >> 16;   // RNE
  return (us)r;
}
static __device__ __forceinline__ float bf2f(us u) {
  unsigned int v = ((unsigned int)u) << 16;
  return __uint_as_float(v);
}

// ---------------- weight prepack: [j(256)][kt(48)][lane(64)][8] ----------------
// block j owns preact cols p = 16j+q, q in [0,16): gate g=q>>2, r=q&3, hd=4j+r
__global__ void pack_w(const float* __restrict__ wxi, const float* __restrict__ wxf,
                       const float* __restrict__ wxo, const float* __restrict__ wxc,
                       const float* __restrict__ whi, const float* __restrict__ whf,
                       const float* __restrict__ who, const float* __restrict__ whc,
                       us* __restrict__ Whip, us* __restrict__ Wlop) {
  int idx = blockIdx.x * 256 + threadIdx.x;       // 256*48*64 = 786432
  int lane = idx & 63;
  int kt   = (idx >> 6) % 48;
  int j    = idx / (48 * 64);
  int q = lane & 15, g = q >> 2, r = q & 3;
  int hd = 4 * j + r;
  int kb = kt * 32 + ((lane >> 4) << 3);
  const float* wx = (g == 0) ? wxi : (g == 1) ? wxf : (g == 2) ? wxo : wxc;
  const float* wh = (g == 0) ? whi : (g == 1) ? whf : (g == 2) ? who : whc;
  long obase = (long)idx * 8;
  #pragma unroll
  for (int jj = 0; jj < 8; ++jj) {
    int k = kb + jj;
    float v = (k < EMBN) ? wx[(long)k * HIDN + hd] : wh[(long)(k - EMBN) * HIDN + hd];
    us hi = f2bf(v);
    us lo = f2bf(v - bf2f(hi));
    Whip[obase + jj] = hi;
    Wlop[obase + jj] = lo;
  }
}

// ---------------- embedding gather + hi/lo split: X[t][b][k] ----------------
__global__ void pack_x(const int* __restrict__ tokens, const float* __restrict__ emb,
                       us* __restrict__ Xhi, us* __restrict__ Xlo) {
  int idx = blockIdx.x * 256 + threadIdx.x;       // 256*64*512 = 8388608
  int k = idx & 511;
  int b = (idx >> 9) & 63;
  int t = idx >> 15;
  int tok = tokens[b * SSN + t];
  float v = emb[(long)tok * EMBN + k];
  us hi = f2bf(v);
  Xhi[idx] = hi;
  Xlo[idx] = f2bf(v - bf2f(hi));
}

// chunk = 4 kt (4 hi + 4 lo frags = 8 bf16x8 = 32 VGPR)
#define XISS(A, c) { _Pragma("unroll") for (int q = 0; q < 4; ++q) { \
      A[2*q]   = *(const bf16x8*)(xh + (((c)*4 + q) << 5)); \
      A[2*q+1] = *(const bf16x8*)(xl + (((c)*4 + q) << 5)); } }
#define XCON(A, c) { _Pragma("unroll") for (int q = 0; q < 4; ++q) { \
      const int kt = (c)*4 + q; \
      bf16x8 w0 = *(const bf16x8*)(WHi + (kt << 9) + (lane << 3)); \
      bf16x8 w1 = *(const bf16x8*)(WLo + (kt << 9) + (lane << 3)); \
      accA = __builtin_amdgcn_mfma_f32_16x16x32_bf16(w0, A[2*q],   accA, 0, 0, 0); \
      accB = __builtin_amdgcn_mfma_f32_16x16x32_bf16(w0, A[2*q+1], accB, 0, 0, 0); \
      accC = __builtin_amdgcn_mfma_f32_16x16x32_bf16(w1, A[2*q],   accC, 0, 0, 0); } }
#define HISS(A, c) { _Pragma("unroll") for (int q = 0; q < 4; ++q) { \
      A[2*q]   = *(const bf16x8*)(hh + (((c)*4 + q) << 5)); \
      A[2*q+1] = *(const bf16x8*)(hl + (((c)*4 + q) << 5)); } }
#define HCON(A, c) { _Pragma("unroll") for (int q = 0; q < 4; ++q) { \
      const int kt = 16 + (c)*4 + q; \
      bf16x8 w0 = *(const bf16x8*)(WHi + (kt << 9) + (lane << 3)); \
      bf16x8 w1 = *(const bf16x8*)(WLo + (kt << 9) + (lane << 3)); \
      accA = __builtin_amdgcn_mfma_f32_16x16x32_bf16(w0, A[2*q],   accA, 0, 0, 0); \
      accB = __builtin_amdgcn_mfma_f32_16x16x32_bf16(w0, A[2*q+1], accB, 0, 0, 0); \
      accC = __builtin_amdgcn_mfma_f32_16x16x32_bf16(w1, A[2*q],   accC, 0, 0, 0); } }

// ---------------- persistent LSTM recurrence ----------------
// 256 blocks x 256 threads (4 waves, one per SIMD). Wave wv = batches [16wv,16wv+16).
// LDS: Whi 48K | Wlo 48K | preact 5120 = 103424 B  -> 1 block/CU
__launch_bounds__(256, 1)
__global__ void lstm_persist(const us* __restrict__ Whip, const us* __restrict__ Wlop,
                             const us* __restrict__ Xhi, const us* __restrict__ Xlo,
                             us* Hhi, us* Hlo, float* hfin, int* flags,
                             const float* __restrict__ biP, const float* __restrict__ bfP,
                             const float* __restrict__ boP, const float* __restrict__ bcP,
                             int useInv) {
  extern __shared__ char smem[];
  us* WHi = (us*)smem;                         // 24576 shorts
  us* WLo = WHi + 24576;                       // 24576 shorts
  float* preact = (float*)(smem + 98304);      // [64][PSTR]

  const int j = blockIdx.x, tid = threadIdx.x;
  const int wv = tid >> 6, lane = tid & 63;

  // one-time: W slices -> LDS (fragment layout identical, straight copy)
  {
    const uint4* shi = (const uint4*)(Whip + (long)j * 24576);
    const uint4* slo = (const uint4*)(Wlop + (long)j * 24576);
    uint4* dhi = (uint4*)WHi;
    uint4* dlo = (uint4*)WLo;
    for (int i = tid; i < 3072; i += 256) { dhi[i] = shi[i]; dlo[i] = slo[i]; }
  }
  // gate mapping: thread -> (b = tid>>2, r = tid&3); c-state in register
  const int gb = tid >> 2, gr = tid & 3;
  const float bi_r = biP[4 * j + gr], bf_r = bfP[4 * j + gr];
  const float bo_r = boP[4 * j + gr], bc_r = bcP[4 * j + gr];
  float c_reg = 0.f;

  const int mrow = (wv << 4) + (lane & 15);    // batch row (MFMA N-dim)
  const int kj = (lane >> 4) << 3;
  const int p0 = (lane >> 4) << 2;
  __syncthreads();

  #pragma unroll 1
  for (int t = 0; t < SSN; ++t) {
    f32x4 accA = {0.f, 0.f, 0.f, 0.f};
    f32x4 accB = {0.f, 0.f, 0.f, 0.f};
    f32x4 accC = {0.f, 0.f, 0.f, 0.f};

    // ---- X part: 4 chunks, 2-deep pipeline (latency hidden by producer slack) ----
    {
      const us* xh = Xhi + ((long)t << 15) + (mrow << 9) + kj;
      const us* xl = Xlo + ((long)t << 15) + (mrow << 9) + kj;
      bf16x8 XA[8], XB[8];
      XISS(XA, 0) XISS(XB, 1)
      __builtin_amdgcn_sched_barrier(0);
      XCON(XA, 0) XISS(XA, 2)
      __builtin_amdgcn_sched_barrier(0);
      XCON(XB, 1) XISS(XB, 3)
      __builtin_amdgcn_sched_barrier(0);
      XCON(XA, 2) XCON(XB, 3)
    }

    if (t > 0) {
      // ---- spin: each thread polls its own flag; s_sleep throttles the LLC
      //      atomic-load storm (65K pollers hammering 16 lines otherwise) ----
      while (__hip_atomic_load(&flags[tid], __ATOMIC_RELAXED, __HIP_MEMORY_SCOPE_AGENT) < t) {
        __builtin_amdgcn_s_sleep(1);
      }
      __syncthreads();
      if (useInv) __builtin_amdgcn_fence(__ATOMIC_ACQUIRE, "agent");

      // ---- H part: 8 chunks, 4-deep load/MFMA pipeline ----
      const int cur = useInv ? (t % 3) : t;
      const us* hh = Hhi + (((long)cur * BBN + mrow) << 10) + kj;
      const us* hl = Hlo + (((long)cur * BBN + mrow) << 10) + kj;
      bf16x8 HA[8], HB[8], HC[8], HD[8];
      HISS(HA, 0) HISS(HB, 1) HISS(HC, 2) HISS(HD, 3)
      __builtin_amdgcn_sched_barrier(0);
      HCON(HA, 0) HISS(HA, 4)
      __builtin_amdgcn_sched_barrier(0);
      HCON(HB, 1) HISS(HB, 5)
      __builtin_amdgcn_sched_barrier(0);
      HCON(HC, 2) HISS(HC, 6)
      __builtin_amdgcn_sched_barrier(0);
      HCON(HD, 3) HISS(HD, 7)
      __builtin_amdgcn_sched_barrier(0);
      HCON(HA, 4) HCON(HB, 5) HCON(HC, 6) HCON(HD, 7)
    }

    // ---- preact: lane holds D[p0+rg][mrow]; 16B LDS store ----
    {
      f32x4 acc = accA + accB;
      acc = acc + accC;
      *(f32x4*)(preact + mrow * PSTR + p0) = acc;
    }
    __syncthreads();

    // ---- gates: one (b,r) per thread; 4-lane shfl gather -> 8B coalesced
    //      agent stores (was 2x2B per thread: 512 sub-line RMW writes/block) ----
    {
      float pi = preact[gb * PSTR + gr]      + bi_r;
      float pf = preact[gb * PSTR + 4 + gr]  + bf_r;
      float po = preact[gb * PSTR + 8 + gr]  + bo_r;
      float pc = preact[gb * PSTR + 12 + gr] + bc_r;
      float vi = 1.f / (1.f + expf(-pi));
      float vf = 1.f / (1.f + expf(-pf));
      float vo = 1.f / (1.f + expf(-po));
      float vc = tanhf(pc);
      c_reg = vf * c_reg + vi * vc;
      float h = vo * tanhf(c_reg);
      if (t == SSN - 1) hfin[(gb << 10) + 4 * j + gr] = h;
      us hh_ = f2bf(h);
      us hl_ = f2bf(h - bf2f(hh_));

      // pack (hi,lo) of the 4 dims of this lane-group into two 8B quads on lane gr==0
      unsigned int hpair = (unsigned int)hh_ | ((unsigned int)hl_ << 16);
      const int base = lane & ~3;
      unsigned int g0 = (unsigned int)__shfl((int)hpair, base);
      unsigned int g1 = (unsigned int)__shfl((int)hpair, base + 1);
      unsigned int g2 = (unsigned int)__shfl((int)hpair, base + 2);
      unsigned int g3 = (unsigned int)__shfl((int)hpair, base + 3);
      unsigned int hi01 = (g0 & 0xffffu) | (g1 << 16);
      unsigned int hi23 = (g2 & 0xffffu) | (g3 << 16);
      unsigned int lo01 = (g0 >> 16)     | (g1 & 0xffff0000u);
      unsigned int lo23 = (g2 >> 16)     | (g3 & 0xffff0000u);
      ull hiq = ((ull)hi23 << 32) | (ull)hi01;
      ull loq = ((ull)lo23 << 32) | (ull)lo01;

      if (!useInv) {
        const long nxt = t + 1;   // fresh slot per step: no cache maintenance needed
        if (gr == 0) {
          __hip_atomic_store((ull*)(Hhi + ((nxt * BBN + gb) << 10) + 4 * j), hiq,
                             __ATOMIC_RELAXED, __HIP_MEMORY_SCOPE_AGENT);
          __hip_atomic_store((ull*)(Hlo + ((nxt * BBN + gb) << 10) + 4 * j), loq,
                             __ATOMIC_RELAXED, __HIP_MEMORY_SCOPE_AGENT);
        }
        asm volatile("s_waitcnt vmcnt(0)" ::: "memory");   // this wave's stores acked
        __syncthreads();                                   // all waves acked
        if (tid == 0)
          __hip_atomic_store(&flags[j], t + 1, __ATOMIC_RELAXED, __HIP_MEMORY_SCOPE_AGENT);
      } else {
        const long nxt = (t + 1) % 3;
        if (gr == 0) {
          *(ull*)(Hhi + ((nxt * BBN + gb) << 10) + 4 * j) = hiq;
          *(ull*)(Hlo + ((nxt * BBN + gb) << 10) + 4 * j) = loq;
        }
        __syncthreads();
        if (tid == 0)   // release: waitcnt + wbL2 emitted by compiler
          __hip_atomic_store(&flags[j], t + 1, __ATOMIC_RELEASE, __HIP_MEMORY_SCOPE_AGENT);
      }
    }
  }
}

// ---------------- output GEMM: out = h_S @ W_hy + b_hy (fp32) ----------------
__global__ void out_gemm(const float* __restrict__ hfin, const float* __restrict__ Why,
                         const float* __restrict__ bhy, float* __restrict__ out) {
  int b = blockIdx.x, n = threadIdx.x;
  const float* h = hfin + (b << 10);
  float acc = 0.f;
  #pragma unroll 8
  for (int k = 0; k < HIDN; ++k) acc = fmaf(h[k], Why[(k << 9) + n], acc);
  out[(b << 9) + n] = acc + bhy[n];
}

// ---------------- launch ----------------
extern "C" void kernel_launch(void* const* d_in, const int* in_sizes, int n_in,
                              void* d_out, int out_size, void* d_ws, size_t ws_size,
                              hipStream_t stream) {
  const int*   tokens = (const int*)d_in[0];
  const float* emb    = (const float*)d_in[1];
  const float* Wxi    = (const float*)d_in[2];
  const float* Wxf    = (const float*)d_in[3];
  const float* Wxo    = (const float*)d_in[4];
  const float* Wxc    = (const float*)d_in[5];
  const float* Whi_   = (const float*)d_in[6];
  const float* Whf    = (const float*)d_in[7];
  const float* Who    = (const float*)d_in[8];
  const float* Whc    = (const float*)d_in[9];
  const float* Why    = (const float*)d_in[10];
  const float* bi     = (const float*)d_in[11];
  const float* bfv    = (const float*)d_in[12];
  const float* bo     = (const float*)d_in[13];
  const float* bc     = (const float*)d_in[14];
  const float* bhy    = (const float*)d_in[15];
  float* outp = (float*)d_out;

  char* ws = (char*)d_ws;
  size_t off = 0;
  auto carve = [&](size_t bytes) -> void* {
    void* p = ws + off;
    off += (bytes + 255) & ~(size_t)255;
    return p;
  };
  us*    Whip = (us*)carve(12582912);
  us*    Wlop = (us*)carve(12582912);
  us*    Xhi  = (us*)carve(16777216);
  us*    Xlo  = (us*)carve(16777216);
  float* hfin = (float*)carve(262144);
  int*   flags = (int*)carve(1024);

  const size_t bigBytes = (size_t)(SSN + 1) * BBN * HIDN * 2;   // 257 slots
  int useInv;
  us *Hhi, *Hlo;
  if (ws_size >= off + 2 * ((bigBytes + 255) & ~(size_t)255)) {
    useInv = 0;
    Hhi = (us*)carve(bigBytes);
    Hlo = (us*)carve(bigBytes);
  } else {
    useInv = 1;
    Hhi = (us*)carve((size_t)3 * BBN * HIDN * 2);
    Hlo = (us*)carve((size_t)3 * BBN * HIDN * 2);
  }

  if (ws_size < off) {   // workspace too small: fail loudly with zero output
    (void)hipMemsetAsync(d_out, 0, (size_t)out_size * 4, stream);
    return;
  }

  (void)hipMemsetAsync(flags, 0, 1024, stream);

  pack_w<<<3072, 256, 0, stream>>>(Wxi, Wxf, Wxo, Wxc, Whi_, Whf, Who, Whc, Whip, Wlop);
  pack_x<<<32768, 256, 0, stream>>>(tokens, emb, Xhi, Xlo);

  (void)hipFuncSetAttribute((const void*)lstm_persist,
                            hipFuncAttributeMaxDynamicSharedMemorySize, 103424);
  lstm_persist<<<NBLK, 256, 103424, stream>>>(Whip, Wlop, Xhi, Xlo, Hhi, Hlo,
                                              hfin, flags, bi, bfv, bo, bc, useInv);
  out_gemm<<<BBN, OUTN, 0, stream>>>(hfin, Why, bhy, outp);
}

// Round 2
// 3149.521 us; speedup vs baseline: 1.0099x; 1.0099x over previous
//
#include <hip/hip_runtime.h>
#include <hip/hip_bf16.h>

// ---------------- problem constants ----------------
#define EMBN   512
#define HIDN   1024
#define OUTN   512
#define BBN    64
#define SSN    256
#define NBLK   256          // persistent blocks; block j owns 4 h-dims x 4 gates = 16 preact cols
#define PSTR   20           // preact LDS row stride (floats)

typedef __attribute__((ext_vector_type(8))) short bf16x8;
typedef __attribute__((ext_vector_type(4))) float f32x4;
typedef __attribute__((ext_vector_type(4))) int int4v;
typedef unsigned short us;
typedef unsigned long long ull;

static __device__ __forceinline__ us f2bf(float x) {
  unsigned int u = __float_as_uint(x);
  unsigned int r = (u + 0x7fffu + ((u >> 16) & 1u)) >> 16;   // RNE
  return (us)r;
}
static __device__ __forceinline__ float bf2f(us u) {
  unsigned int v = ((unsigned int)u) << 16;
  return __uint_as_float(v);
}

// ---------------- weight prepack: [j(256)][kt(48)][lane(64)][8] ----------------
// block j owns preact cols p = 16j+q, q in [0,16): gate g=q>>2, r=q&3, hd=4j+r
__global__ void pack_w(const float* __restrict__ wxi, const float* __restrict__ wxf,
                       const float* __restrict__ wxo, const float* __restrict__ wxc,
                       const float* __restrict__ whi, const float* __restrict__ whf,
                       const float* __restrict__ who, const float* __restrict__ whc,
                       us* __restrict__ Whip, us* __restrict__ Wlop) {
  int idx = blockIdx.x * 256 + threadIdx.x;       // 256*48*64 = 786432
  int lane = idx & 63;
  int kt   = (idx >> 6) % 48;
  int j    = idx / (48 * 64);
  int q = lane & 15, g = q >> 2, r = q & 3;
  int hd = 4 * j + r;
  int kb = kt * 32 + ((lane >> 4) << 3);
  const float* wx = (g == 0) ? wxi : (g == 1) ? wxf : (g == 2) ? wxo : wxc;
  const float* wh = (g == 0) ? whi : (g == 1) ? whf : (g == 2) ? who : whc;
  long obase = (long)idx * 8;
  #pragma unroll
  for (int jj = 0; jj < 8; ++jj) {
    int k = kb + jj;
    float v = (k < EMBN) ? wx[(long)k * HIDN + hd] : wh[(long)(k - EMBN) * HIDN + hd];
    us hi = f2bf(v);
    us lo = f2bf(v - bf2f(hi));
    Whip[obase + jj] = hi;
    Wlop[obase + jj] = lo;
  }
}

// ---------------- embedding gather + hi/lo split: X[t][b][k] ----------------
__global__ void pack_x(const int* __restrict__ tokens, const float* __restrict__ emb,
                       us* __restrict__ Xhi, us* __restrict__ Xlo) {
  int idx = blockIdx.x * 256 + threadIdx.x;       // 256*64*512 = 8388608
  int k = idx & 511;
  int b = (idx >> 9) & 63;
  int t = idx >> 15;
  int tok = tokens[b * SSN + t];
  float v = emb[(long)tok * EMBN + k];
  us hi = f2bf(v);
  Xhi[idx] = hi;
  Xlo[idx] = f2bf(v - bf2f(hi));
}

// chunk = 4 kt (4 hi + 4 lo frags = 8 bf16x8 = 32 VGPR)
#define XISS(A, c) { _Pragma("unroll") for (int q = 0; q < 4; ++q) { \
      A[2*q]   = *(const bf16x8*)(xh + (((c)*4 + q) << 5)); \
      A[2*q+1] = *(const bf16x8*)(xl + (((c)*4 + q) << 5)); } }
#define XCON(A, c) { _Pragma("unroll") for (int q = 0; q < 4; ++q) { \
      const int kt = (c)*4 + q; \
      bf16x8 w0 = *(const bf16x8*)(WHi + (kt << 9) + (lane << 3)); \
      bf16x8 w1 = *(const bf16x8*)(WLo + (kt << 9) + (lane << 3)); \
      accA = __builtin_amdgcn_mfma_f32_16x16x32_bf16(w0, A[2*q],   accA, 0, 0, 0); \
      accB = __builtin_amdgcn_mfma_f32_16x16x32_bf16(w0, A[2*q+1], accB, 0, 0, 0); \
      accC = __builtin_amdgcn_mfma_f32_16x16x32_bf16(w1, A[2*q],   accC, 0, 0, 0); } }
#define HISS(A, c) { _Pragma("unroll") for (int q = 0; q < 4; ++q) { \
      A[2*q]   = *(const bf16x8*)(hh + (((c)*4 + q) << 5)); \
      A[2*q+1] = *(const bf16x8*)(hl + (((c)*4 + q) << 5)); } }
#define HCON(A, c) { _Pragma("unroll") for (int q = 0; q < 4; ++q) { \
      const int kt = 16 + (c)*4 + q; \
      bf16x8 w0 = *(const bf16x8*)(WHi + (kt << 9) + (lane << 3)); \
      bf16x8 w1 = *(const bf16x8*)(WLo + (kt << 9) + (lane << 3)); \
      accA = __builtin_amdgcn_mfma_f32_16x16x32_bf16(w0, A[2*q],   accA, 0, 0, 0); \
      accB = __builtin_amdgcn_mfma_f32_16x16x32_bf16(w0, A[2*q+1], accB, 0, 0, 0); \
      accC = __builtin_amdgcn_mfma_f32_16x16x32_bf16(w1, A[2*q],   accC, 0, 0, 0); } }

// ---------------- persistent LSTM recurrence ----------------
// 256 blocks x 256 threads (4 waves, one per SIMD). Wave wv = batches [16wv,16wv+16).
// LDS: Whi 48K | Wlo 48K | preact 5120 = 103424 B  -> 1 block/CU
// H slots form a power-of-two ring of K slots. K==256 -> no reuse within the
// run (fresh-slot), no cache maintenance. K<256 -> one agent acquire-fence
// every K steps (amortized ~free) to clear stale L1/L2 lines before reuse.
__launch_bounds__(256, 1)
__global__ void lstm_persist(const us* __restrict__ Whip, const us* __restrict__ Wlop,
                             const us* __restrict__ Xhi, const us* __restrict__ Xlo,
                             us* Hhi, us* Hlo, float* hfin, int* flags,
                             const float* __restrict__ biP, const float* __restrict__ bfP,
                             const float* __restrict__ boP, const float* __restrict__ bcP,
                             int K) {
  extern __shared__ char smem[];
  us* WHi = (us*)smem;                         // 24576 shorts
  us* WLo = WHi + 24576;                       // 24576 shorts
  float* preact = (float*)(smem + 98304);      // [64][PSTR]

  const int j = blockIdx.x, tid = threadIdx.x;
  const int wv = tid >> 6, lane = tid & 63;
  const int Km = K - 1;
  const bool ROT = (K != 256);

  // one-time: W slices -> LDS (fragment layout identical, straight copy)
  {
    const uint4* shi = (const uint4*)(Whip + (long)j * 24576);
    const uint4* slo = (const uint4*)(Wlop + (long)j * 24576);
    uint4* dhi = (uint4*)WHi;
    uint4* dlo = (uint4*)WLo;
    for (int i = tid; i < 3072; i += 256) { dhi[i] = shi[i]; dlo[i] = slo[i]; }
  }
  // gate mapping: thread -> (b = tid>>2, r = tid&3); c-state in register
  const int gb = tid >> 2, gr = tid & 3;
  const float bi_r = biP[4 * j + gr], bf_r = bfP[4 * j + gr];
  const float bo_r = boP[4 * j + gr], bc_r = bcP[4 * j + gr];
  float c_reg = 0.f;

  const int mrow = (wv << 4) + (lane & 15);    // batch row (MFMA N-dim)
  const int kj = (lane >> 4) << 3;
  const int p0 = (lane >> 4) << 2;
  __syncthreads();

  #pragma unroll 1
  for (int t = 0; t < SSN; ++t) {
    f32x4 accA = {0.f, 0.f, 0.f, 0.f};
    f32x4 accB = {0.f, 0.f, 0.f, 0.f};
    f32x4 accC = {0.f, 0.f, 0.f, 0.f};

    // ---- X part: 4 chunks, 2-deep pipeline (latency hidden by producer slack) ----
    {
      const us* xh = Xhi + ((long)t << 15) + (mrow << 9) + kj;
      const us* xl = Xlo + ((long)t << 15) + (mrow << 9) + kj;
      bf16x8 XA[8], XB[8];
      XISS(XA, 0) XISS(XB, 1)
      __builtin_amdgcn_sched_barrier(0);
      XCON(XA, 0) XISS(XA, 2)
      __builtin_amdgcn_sched_barrier(0);
      XCON(XB, 1) XISS(XB, 3)
      __builtin_amdgcn_sched_barrier(0);
      XCON(XA, 2) XCON(XB, 3)
    }

    if (t > 0) {
      // ---- spin: ONLY wave 0 polls. One dwordx4 per lane covers all 256
      //      flags (16 line-requests/block/poll vs 64 before; 1 wave vs 4).
      //      sc0 sc1 -> L2-bypassing (coherent) load, same as atomic-agent. ----
      if (wv == 0) {
        const int* fp = flags + (lane << 2);
        int4v f;
        do {
          asm volatile("global_load_dwordx4 %0, %1, off sc0 sc1\n\t"
                       "s_waitcnt vmcnt(0)"
                       : "=&v"(f) : "v"(fp) : "memory");
        } while (__any((f.x < t) | (f.y < t) | (f.z < t) | (f.w < t)));
      }
      __syncthreads();
      if (ROT && (t & Km) == 0)
        __builtin_amdgcn_fence(__ATOMIC_ACQUIRE, "agent");   // slot-ring wrap: clear stale lines

      // ---- H part: 8 chunks, 4-deep load/MFMA pipeline ----
      const int cur = t & Km;
      const us* hh = Hhi + (((long)cur * BBN + mrow) << 10) + kj;
      const us* hl = Hlo + (((long)cur * BBN + mrow) << 10) + kj;
      bf16x8 HA[8], HB[8], HC[8], HD[8];
      HISS(HA, 0) HISS(HB, 1) HISS(HC, 2) HISS(HD, 3)
      __builtin_amdgcn_sched_barrier(0);
      HCON(HA, 0) HISS(HA, 4)
      __builtin_amdgcn_sched_barrier(0);
      HCON(HB, 1) HISS(HB, 5)
      __builtin_amdgcn_sched_barrier(0);
      HCON(HC, 2) HISS(HC, 6)
      __builtin_amdgcn_sched_barrier(0);
      HCON(HD, 3) HISS(HD, 7)
      __builtin_amdgcn_sched_barrier(0);
      HCON(HA, 4) HCON(HB, 5) HCON(HC, 6) HCON(HD, 7)
    }

    // ---- preact: lane holds D[p0+rg][mrow]; 16B LDS store ----
    {
      f32x4 acc = accA + accB;
      acc = acc + accC;
      *(f32x4*)(preact + mrow * PSTR + p0) = acc;
    }
    __syncthreads();

    // ---- gates: one (b,r) per thread; 4-lane shfl gather -> 8B coalesced stores ----
    {
      float pi = preact[gb * PSTR + gr]      + bi_r;
      float pf = preact[gb * PSTR + 4 + gr]  + bf_r;
      float po = preact[gb * PSTR + 8 + gr]  + bo_r;
      float pc = preact[gb * PSTR + 12 + gr] + bc_r;
      float vi = 1.f / (1.f + expf(-pi));
      float vf = 1.f / (1.f + expf(-pf));
      float vo = 1.f / (1.f + expf(-po));
      float vc = tanhf(pc);
      c_reg = vf * c_reg + vi * vc;
      float h = vo * tanhf(c_reg);
      if (t == SSN - 1) hfin[(gb << 10) + 4 * j + gr] = h;
      us hh_ = f2bf(h);
      us hl_ = f2bf(h - bf2f(hh_));

      // pack (hi,lo) of the 4 dims of this lane-group into two 8B quads on lane gr==0
      unsigned int hpair = (unsigned int)hh_ | ((unsigned int)hl_ << 16);
      const int base = lane & ~3;
      unsigned int g0 = (unsigned int)__shfl((int)hpair, base);
      unsigned int g1 = (unsigned int)__shfl((int)hpair, base + 1);
      unsigned int g2 = (unsigned int)__shfl((int)hpair, base + 2);
      unsigned int g3 = (unsigned int)__shfl((int)hpair, base + 3);
      unsigned int hi01 = (g0 & 0xffffu) | (g1 << 16);
      unsigned int hi23 = (g2 & 0xffffu) | (g3 << 16);
      unsigned int lo01 = (g0 >> 16)     | (g1 & 0xffff0000u);
      unsigned int lo23 = (g2 >> 16)     | (g3 & 0xffff0000u);
      ull hiq = ((ull)hi23 << 32) | (ull)hi01;
      ull loq = ((ull)lo23 << 32) | (ull)lo01;

      const long nxt = (t + 1) & Km;   // ring slot; unread before write (K-deep)
      if (gr == 0) {
        __hip_atomic_store((ull*)(Hhi + ((nxt * BBN + gb) << 10) + 4 * j), hiq,
                           __ATOMIC_RELAXED, __HIP_MEMORY_SCOPE_AGENT);
        __hip_atomic_store((ull*)(Hlo + ((nxt * BBN + gb) << 10) + 4 * j), loq,
                           __ATOMIC_RELAXED, __HIP_MEMORY_SCOPE_AGENT);
      }
      asm volatile("s_waitcnt vmcnt(0)" ::: "memory");   // this wave's stores acked in LLC
      __syncthreads();                                   // all waves acked
      if (tid == 0)
        __hip_atomic_store(&flags[j], t + 1, __ATOMIC_RELAXED, __HIP_MEMORY_SCOPE_AGENT);
    }
  }
}

// ---------------- output GEMM: out = h_S @ W_hy + b_hy (fp32) ----------------
__global__ void out_gemm(const float* __restrict__ hfin, const float* __restrict__ Why,
                         const float* __restrict__ bhy, float* __restrict__ out) {
  int b = blockIdx.x, n = threadIdx.x;
  const float* h = hfin + (b << 10);
  float acc = 0.f;
  #pragma unroll 8
  for (int k = 0; k < HIDN; ++k) acc = fmaf(h[k], Why[(k << 9) + n], acc);
  out[(b << 9) + n] = acc + bhy[n];
}

// ---------------- launch ----------------
extern "C" void kernel_launch(void* const* d_in, const int* in_sizes, int n_in,
                              void* d_out, int out_size, void* d_ws, size_t ws_size,
                              hipStream_t stream) {
  const int*   tokens = (const int*)d_in[0];
  const float* emb    = (const float*)d_in[1];
  const float* Wxi    = (const float*)d_in[2];
  const float* Wxf    = (const float*)d_in[3];
  const float* Wxo    = (const float*)d_in[4];
  const float* Wxc    = (const float*)d_in[5];
  const float* Whi_   = (const float*)d_in[6];
  const float* Whf    = (const float*)d_in[7];
  const float* Who    = (const float*)d_in[8];
  const float* Whc    = (const float*)d_in[9];
  const float* Why    = (const float*)d_in[10];
  const float* bi     = (const float*)d_in[11];
  const float* bfv    = (const float*)d_in[12];
  const float* bo     = (const float*)d_in[13];
  const float* bc     = (const float*)d_in[14];
  const float* bhy    = (const float*)d_in[15];
  float* outp = (float*)d_out;

  char* ws = (char*)d_ws;
  size_t off = 0;
  auto carve = [&](size_t bytes) -> void* {
    void* p = ws + off;
    off += (bytes + 255) & ~(size_t)255;
    return p;
  };
  us*    Whip = (us*)carve(12582912);
  us*    Wlop = (us*)carve(12582912);
  us*    Xhi  = (us*)carve(16777216);
  us*    Xlo  = (us*)carve(16777216);
  float* hfin = (float*)carve(262144);
  int*   flags = (int*)carve(1024);

  // rotation depth: largest power-of-two slot count (<=256) that fits.
  // K=256 -> zero reuse during the run (no fences at all).
  size_t rem = (ws_size > off) ? (ws_size - off) : 0;
  int K = 256;
  while (K > 4 && (size_t)2 * (size_t)K * 131072 + 512 > rem) K >>= 1;
  if ((size_t)2 * (size_t)K * 131072 + 512 > rem) {
    (void)hipMemsetAsync(d_out, 0, (size_t)out_size * 4, stream);  // workspace too small
    return;
  }
  us* Hhi = (us*)carve((size_t)K * 131072);
  us* Hlo = (us*)carve((size_t)K * 131072);

  (void)hipMemsetAsync(flags, 0, 1024, stream);

  pack_w<<<3072, 256, 0, stream>>>(Wxi, Wxf, Wxo, Wxc, Whi_, Whf, Who, Whc, Whip, Wlop);
  pack_x<<<32768, 256, 0, stream>>>(tokens, emb, Xhi, Xlo);

  (void)hipFuncSetAttribute((const void*)lstm_persist,
                            hipFuncAttributeMaxDynamicSharedMemorySize, 103424);
  lstm_persist<<<NBLK, 256, 103424, stream>>>(Whip, Wlop, Xhi, Xlo, Hhi, Hlo,
                                              hfin, flags, bi, bfv, bo, bc, K);
  out_gemm<<<BBN, OUTN, 0, stream>>>(hfin, Why, bhy, outp);
}

// Round 3
// 2820.978 us; speedup vs baseline: 1.1275x; 1.1165x over previous
//
#include <hip/hip_runtime.h>
#include <hip/hip_bf16.h>

// ---------------- problem constants ----------------
#define EMBN   512
#define HIDN   1024
#define OUTN   512
#define BBN    64
#define SSN    256
#define NBLK   256          // persistent blocks; block j owns 4 h-dims x 4 gates = 16 preact cols
#define PSTR   20           // preact LDS row stride (floats)

typedef __attribute__((ext_vector_type(8))) short bf16x8;
typedef __attribute__((ext_vector_type(4))) float f32x4;
typedef __attribute__((ext_vector_type(4))) int int4v;
typedef unsigned short us;
typedef unsigned long long ull;

static __device__ __forceinline__ us f2bf(float x) {
  unsigned int u = __float_as_uint(x);
  unsigned int r = (u + 0x7fffu + ((u >> 16) & 1u)) >> 16;   // RNE
  return (us)r;
}
static __device__ __forceinline__ float bf2f(us u) {
  unsigned int v = ((unsigned int)u) << 16;
  return __uint_as_float(v);
}

// ---------------- weight prepack: [j(256)][kt(48)][lane(64)][8] ----------------
// block j owns preact cols p = 16j+q, q in [0,16): gate g=q>>2, r=q&3, hd=4j+r
__global__ void pack_w(const float* __restrict__ wxi, const float* __restrict__ wxf,
                       const float* __restrict__ wxo, const float* __restrict__ wxc,
                       const float* __restrict__ whi, const float* __restrict__ whf,
                       const float* __restrict__ who, const float* __restrict__ whc,
                       us* __restrict__ Whip, us* __restrict__ Wlop) {
  int idx = blockIdx.x * 256 + threadIdx.x;       // 256*48*64 = 786432
  int lane = idx & 63;
  int kt   = (idx >> 6) % 48;
  int j    = idx / (48 * 64);
  int q = lane & 15, g = q >> 2, r = q & 3;
  int hd = 4 * j + r;
  int kb = kt * 32 + ((lane >> 4) << 3);
  const float* wx = (g == 0) ? wxi : (g == 1) ? wxf : (g == 2) ? wxo : wxc;
  const float* wh = (g == 0) ? whi : (g == 1) ? whf : (g == 2) ? who : whc;
  long obase = (long)idx * 8;
  #pragma unroll
  for (int jj = 0; jj < 8; ++jj) {
    int k = kb + jj;
    float v = (k < EMBN) ? wx[(long)k * HIDN + hd] : wh[(long)(k - EMBN) * HIDN + hd];
    us hi = f2bf(v);
    us lo = f2bf(v - bf2f(hi));
    Whip[obase + jj] = hi;
    Wlop[obase + jj] = lo;
  }
}

// ---------------- embedding gather + hi/lo split: X[t][b][k] ----------------
__global__ void pack_x(const int* __restrict__ tokens, const float* __restrict__ emb,
                       us* __restrict__ Xhi, us* __restrict__ Xlo) {
  int idx = blockIdx.x * 256 + threadIdx.x;       // 256*64*512 = 8388608
  int k = idx & 511;
  int b = (idx >> 9) & 63;
  int t = idx >> 15;
  int tok = tokens[b * SSN + t];
  float v = emb[(long)tok * EMBN + k];
  us hi = f2bf(v);
  Xhi[idx] = hi;
  Xlo[idx] = f2bf(v - bf2f(hi));
}

// chunk = 4 kt (4 hi + 4 lo frags = 8 bf16x8 = 32 VGPR)
#define XISS(A, c) { _Pragma("unroll") for (int q = 0; q < 4; ++q) { \
      A[2*q]   = *(const bf16x8*)(xh + (((c)*4 + q) << 5)); \
      A[2*q+1] = *(const bf16x8*)(xl + (((c)*4 + q) << 5)); } }
#define XCON(A, c) { _Pragma("unroll") for (int q = 0; q < 4; ++q) { \
      const int kt = (c)*4 + q; \
      bf16x8 w0 = *(const bf16x8*)(WHi + (kt << 9) + (lane << 3)); \
      bf16x8 w1 = *(const bf16x8*)(WLo + (kt << 9) + (lane << 3)); \
      accA = __builtin_amdgcn_mfma_f32_16x16x32_bf16(w0, A[2*q],   accA, 0, 0, 0); \
      accB = __builtin_amdgcn_mfma_f32_16x16x32_bf16(w0, A[2*q+1], accB, 0, 0, 0); \
      accC = __builtin_amdgcn_mfma_f32_16x16x32_bf16(w1, A[2*q],   accC, 0, 0, 0); } }
#define HISS(A, c) { _Pragma("unroll") for (int q = 0; q < 4; ++q) { \
      A[2*q]   = *(const bf16x8*)(hh + (((c)*4 + q) << 5)); \
      A[2*q+1] = *(const bf16x8*)(hl + (((c)*4 + q) << 5)); } }
#define HCON(A, c) { _Pragma("unroll") for (int q = 0; q < 4; ++q) { \
      const int kt = 16 + (c)*4 + q; \
      bf16x8 w0 = *(const bf16x8*)(WHi + (kt << 9) + (lane << 3)); \
      bf16x8 w1 = *(const bf16x8*)(WLo + (kt << 9) + (lane << 3)); \
      accA = __builtin_amdgcn_mfma_f32_16x16x32_bf16(w0, A[2*q],   accA, 0, 0, 0); \
      accB = __builtin_amdgcn_mfma_f32_16x16x32_bf16(w0, A[2*q+1], accB, 0, 0, 0); \
      accC = __builtin_amdgcn_mfma_f32_16x16x32_bf16(w1, A[2*q],   accC, 0, 0, 0); } }

// ---------------- persistent LSTM recurrence ----------------
// 256 blocks x 256 threads (4 waves, one per SIMD). Wave wv = batches [16wv,16wv+16).
// Waves are FULLY decoupled: the preact->gates exchange is intra-wave (LDS rows
// partition by wave), and plane wv = {wave wv of all 256 blocks} communicates
// only within itself via flags[wv][j]. No __syncthreads in the loop.
// Protocol per wave per step t: poll plane flags >= t -> cached H loads -> MFMA
// -> gates -> h stores(slot t+1, sc0sc1) -> issue X loads(t+1) -> vmcnt(0)
// (ack hidden under X-load latency) -> flag[wv][j]=t+1 -> X MFMAs.
// Ring reuse safe: writer of slot t+1 saw all plane flags >= t  => within-plane
// skew < 3 slots << K. Different planes touch disjoint rows.
__launch_bounds__(256, 1)
__global__ void lstm_persist(const us* __restrict__ Whip, const us* __restrict__ Wlop,
                             const us* __restrict__ Xhi, const us* __restrict__ Xlo,
                             us* Hhi, us* Hlo, float* hfin, int* flags,
                             const float* __restrict__ biP, const float* __restrict__ bfP,
                             const float* __restrict__ boP, const float* __restrict__ bcP,
                             int K) {
  extern __shared__ char smem[];
  us* WHi = (us*)smem;                         // 24576 shorts
  us* WLo = WHi + 24576;                       // 24576 shorts
  float* preact = (float*)(smem + 98304);      // [64][PSTR], rows partition by wave

  const int j = blockIdx.x, tid = threadIdx.x;
  const int wv = tid >> 6, lane = tid & 63;
  const int Km = K - 1;
  const bool ROT = (K != 256);

  // one-time: W slices -> LDS (fragment layout identical, straight copy)
  {
    const uint4* shi = (const uint4*)(Whip + (long)j * 24576);
    const uint4* slo = (const uint4*)(Wlop + (long)j * 24576);
    uint4* dhi = (uint4*)WHi;
    uint4* dlo = (uint4*)WLo;
    for (int i = tid; i < 3072; i += 256) { dhi[i] = shi[i]; dlo[i] = slo[i]; }
  }
  // gate mapping: thread -> (b = tid>>2, r = tid&3); c-state in register.
  // gb of this thread lies in [16wv,16wv+16) == the rows this wave computes.
  const int gb = tid >> 2, gr = tid & 3;
  const float bi_r = biP[4 * j + gr], bf_r = bfP[4 * j + gr];
  const float bo_r = boP[4 * j + gr], bc_r = bcP[4 * j + gr];
  float c_reg = 0.f;

  const int mrow = (wv << 4) + (lane & 15);    // batch row (MFMA N-dim)
  const int kj = (lane >> 4) << 3;
  const int p0 = (lane >> 4) << 2;
  int* const flagsP = flags + (wv << 8);       // this plane's 256 flags
  __syncthreads();                             // W in LDS ready (only barrier)

  f32x4 accA = {0.f, 0.f, 0.f, 0.f};
  f32x4 accB = {0.f, 0.f, 0.f, 0.f};
  f32x4 accC = {0.f, 0.f, 0.f, 0.f};

  // ---- prologue: acc = X(0) contribution ----
  {
    const us* xh = Xhi + (mrow << 9) + kj;
    const us* xl = Xlo + (mrow << 9) + kj;
    bf16x8 XA[8], XB[8];
    XISS(XA, 0) XISS(XB, 1)
    __builtin_amdgcn_sched_barrier(0);
    XCON(XA, 0) XISS(XA, 2)
    __builtin_amdgcn_sched_barrier(0);
    XCON(XB, 1) XISS(XB, 3)
    __builtin_amdgcn_sched_barrier(0);
    XCON(XA, 2) XCON(XB, 3)
  }

  #pragma unroll 1
  for (int t = 0; t < SSN; ++t) {
    if (t > 0) {
      if (ROT && (t & Km) == 0)
        __builtin_amdgcn_fence(__ATOMIC_ACQUIRE, "agent");  // ring wrap: clear stale L1/L2

      // ---- poll own plane's 256 flags (uncached dwordx4 per lane) ----
      {
        const int* fp = flagsP + (lane << 2);
        int4v f;
        for (;;) {
          asm volatile("global_load_dwordx4 %0, %1, off sc0 sc1\n\t"
                       "s_waitcnt vmcnt(0)"
                       : "=&v"(f) : "v"(fp) : "memory");
          if (!__any((f.x < t) | (f.y < t) | (f.z < t) | (f.w < t))) break;
          __builtin_amdgcn_s_sleep(2);
        }
      }

      // ---- H part: cached loads (flag-gated => lines fresh), 4-deep pipeline ----
      const int cur = t & Km;
      const us* hh = Hhi + (((long)cur * BBN + mrow) << 10) + kj;
      const us* hl = Hlo + (((long)cur * BBN + mrow) << 10) + kj;
      bf16x8 HA[8], HB[8], HC[8], HD[8];
      HISS(HA, 0) HISS(HB, 1) HISS(HC, 2) HISS(HD, 3)
      __builtin_amdgcn_sched_barrier(0);
      HCON(HA, 0) HISS(HA, 4)
      __builtin_amdgcn_sched_barrier(0);
      HCON(HB, 1) HISS(HB, 5)
      __builtin_amdgcn_sched_barrier(0);
      HCON(HC, 2) HISS(HC, 6)
      __builtin_amdgcn_sched_barrier(0);
      HCON(HD, 3) HISS(HD, 7)
      __builtin_amdgcn_sched_barrier(0);
      HCON(HA, 4) HCON(HB, 5) HCON(HC, 6) HCON(HD, 7)
    }

    // ---- preact: lane holds D[p0+rg][mrow]; 16B LDS store (intra-wave rows) ----
    {
      f32x4 acc = accA + accB;
      acc = acc + accC;
      *(f32x4*)(preact + mrow * PSTR + p0) = acc;
    }
    // no barrier: producer lanes and consumer threads are the SAME wave;
    // compiler orders ds_write -> ds_read via lgkmcnt.

    // ---- gates: one (b,r) per thread ----
    {
      float pi = preact[gb * PSTR + gr]      + bi_r;
      float pf = preact[gb * PSTR + 4 + gr]  + bf_r;
      float po = preact[gb * PSTR + 8 + gr]  + bo_r;
      float pc = preact[gb * PSTR + 12 + gr] + bc_r;
      float vi = 1.f / (1.f + expf(-pi));
      float vf = 1.f / (1.f + expf(-pf));
      float vo = 1.f / (1.f + expf(-po));
      float vc = tanhf(pc);
      c_reg = vf * c_reg + vi * vc;
      float h = vo * tanhf(c_reg);

      if (t == SSN - 1) {
        hfin[(gb << 10) + 4 * j + gr] = h;     // last step: only the final h matters
      } else {
        us hh_ = f2bf(h);
        us hl_ = f2bf(h - bf2f(hh_));
        // pack (hi,lo) of the 4 dims of this lane-group into two 8B quads
        unsigned int hpair = (unsigned int)hh_ | ((unsigned int)hl_ << 16);
        const int base = lane & ~3;
        unsigned int g0 = (unsigned int)__shfl((int)hpair, base);
        unsigned int g1 = (unsigned int)__shfl((int)hpair, base + 1);
        unsigned int g2 = (unsigned int)__shfl((int)hpair, base + 2);
        unsigned int g3 = (unsigned int)__shfl((int)hpair, base + 3);
        unsigned int hi01 = (g0 & 0xffffu) | (g1 << 16);
        unsigned int hi23 = (g2 & 0xffffu) | (g3 << 16);
        unsigned int lo01 = (g0 >> 16)     | (g1 & 0xffff0000u);
        unsigned int lo23 = (g2 >> 16)     | (g3 & 0xffff0000u);
        ull hiq = ((ull)hi23 << 32) | (ull)hi01;
        ull loq = ((ull)lo23 << 32) | (ull)lo01;

        const long nxt = (long)((t + 1) & Km);
        if (gr == 0) {
          __hip_atomic_store((ull*)(Hhi + ((nxt * BBN + gb) << 10) + 4 * j), hiq,
                             __ATOMIC_RELAXED, __HIP_MEMORY_SCOPE_AGENT);
          __hip_atomic_store((ull*)(Hlo + ((nxt * BBN + gb) << 10) + 4 * j), loq,
                             __ATOMIC_RELAXED, __HIP_MEMORY_SCOPE_AGENT);
        }

        // ---- X part for t+1: issue first 2 chunks BEFORE the ack wait so the
        //      store-ack hides under X-load latency; flag right after; then MFMA.
        const us* xh = Xhi + ((long)(t + 1) << 15) + (mrow << 9) + kj;
        const us* xl = Xlo + ((long)(t + 1) << 15) + (mrow << 9) + kj;
        bf16x8 XA[8], XB[8];
        XISS(XA, 0) XISS(XB, 1)
        asm volatile("s_waitcnt vmcnt(0)" ::: "memory");  // h stores acked (wave counter)
        if (lane == 0)
          __hip_atomic_store(&flagsP[j], t + 1,
                             __ATOMIC_RELAXED, __HIP_MEMORY_SCOPE_AGENT);
        __builtin_amdgcn_sched_barrier(0);
        accA = {0.f, 0.f, 0.f, 0.f};
        accB = {0.f, 0.f, 0.f, 0.f};
        accC = {0.f, 0.f, 0.f, 0.f};
        XCON(XA, 0) XISS(XA, 2)
        __builtin_amdgcn_sched_barrier(0);
        XCON(XB, 1) XISS(XB, 3)
        __builtin_amdgcn_sched_barrier(0);
        XCON(XA, 2) XCON(XB, 3)
      }
    }
  }
}

// ---------------- output GEMM: out = h_S @ W_hy + b_hy (fp32) ----------------
__global__ void out_gemm(const float* __restrict__ hfin, const float* __restrict__ Why,
                         const float* __restrict__ bhy, float* __restrict__ out) {
  int b = blockIdx.x, n = threadIdx.x;
  const float* h = hfin + (b << 10);
  float acc = 0.f;
  #pragma unroll 8
  for (int k = 0; k < HIDN; ++k) acc = fmaf(h[k], Why[(k << 9) + n], acc);
  out[(b << 9) + n] = acc + bhy[n];
}

// ---------------- launch ----------------
extern "C" void kernel_launch(void* const* d_in, const int* in_sizes, int n_in,
                              void* d_out, int out_size, void* d_ws, size_t ws_size,
                              hipStream_t stream) {
  const int*   tokens = (const int*)d_in[0];
  const float* emb    = (const float*)d_in[1];
  const float* Wxi    = (const float*)d_in[2];
  const float* Wxf    = (const float*)d_in[3];
  const float* Wxo    = (const float*)d_in[4];
  const float* Wxc    = (const float*)d_in[5];
  const float* Whi_   = (const float*)d_in[6];
  const float* Whf    = (const float*)d_in[7];
  const float* Who    = (const float*)d_in[8];
  const float* Whc    = (const float*)d_in[9];
  const float* Why    = (const float*)d_in[10];
  const float* bi     = (const float*)d_in[11];
  const float* bfv    = (const float*)d_in[12];
  const float* bo     = (const float*)d_in[13];
  const float* bc     = (const float*)d_in[14];
  const float* bhy    = (const float*)d_in[15];
  float* outp = (float*)d_out;

  char* ws = (char*)d_ws;
  size_t off = 0;
  auto carve = [&](size_t bytes) -> void* {
    void* p = ws + off;
    off += (bytes + 255) & ~(size_t)255;
    return p;
  };
  us*    Whip = (us*)carve(12582912);
  us*    Wlop = (us*)carve(12582912);
  us*    Xhi  = (us*)carve(16777216);
  us*    Xlo  = (us*)carve(16777216);
  float* hfin = (float*)carve(262144);
  int*   flags = (int*)carve(4096);            // [4 planes][256 blocks]

  // rotation depth: largest power-of-two slot count (<=256) that fits.
  // K=256 -> zero reuse during the run (no fences at all).
  size_t rem = (ws_size > off) ? (ws_size - off) : 0;
  int K = 256;
  while (K > 8 && (size_t)2 * (size_t)K * 131072 + 512 > rem) K >>= 1;
  if ((size_t)2 * (size_t)K * 131072 + 512 > rem) {
    (void)hipMemsetAsync(d_out, 0, (size_t)out_size * 4, stream);  // workspace too small
    return;
  }
  us* Hhi = (us*)carve((size_t)K * 131072);
  us* Hlo = (us*)carve((size_t)K * 131072);

  (void)hipMemsetAsync(flags, 0, 4096, stream);

  pack_w<<<3072, 256, 0, stream>>>(Wxi, Wxf, Wxo, Wxc, Whi_, Whf, Who, Whc, Whip, Wlop);
  pack_x<<<32768, 256, 0, stream>>>(tokens, emb, Xhi, Xlo);

  (void)hipFuncSetAttribute((const void*)lstm_persist,
                            hipFuncAttributeMaxDynamicSharedMemorySize, 103424);
  lstm_persist<<<NBLK, 256, 103424, stream>>>(Whip, Wlop, Xhi, Xlo, Hhi, Hlo,
                                              hfin, flags, bi, bfv, bo, bc, K);
  out_gemm<<<BBN, OUTN, 0, stream>>>(hfin, Why, bhy, outp);
}